// Round 5
// baseline (1392.012 us; speedup 1.0000x reference)
//
#include <hip/hip_runtime.h>
#include <math.h>

// ---------------- problem constants ----------------
#define NV    50257
#define OUT_M 402056            // 8*50257
#define OUT_A 402568            // + 8*64
#define SCALE 0.125f            // 1/sqrt(64)

// ---------------- ws layout (float offsets) ----------------
#define WS_Q      0             // [8][64][64]
#define WS_HTR    32768         // [1024][8]
#define WS_S      40960         // [64][64]  S = WG Sigma WG^T
#define WS_TV     45056         // [64]
#define WS_C0     45120         // [1]
#define WS_HLIE   47144         // [8][64]
#define WS_W1     47656         // [8][64]
#define WS_GH     48176         // [8]
#define WS_WMAT   48192         // [8][64][64]  W = Q G Q^T
#define WS_SC     80960         // [8][256] scores
#define WS_WB     83008         // [8][64]
#define WS_CONSTB 83520         // [8]
#define WS_GAMMA  83528         // [8]
#define WS_CT     83536         // [8][64]
#define WS_P6     84048         // [8][4][20] top-k partials
// partial-GEMV regions
#define WS_PQT    86016         // [16][8][64]  q_t partials
#define WS_PHL    94208         // [16][8][64]  h_lie partials
#define WS_PGH    102400        // [16][8]      gamma_h partials
#define WS_PGP    102528        // [32][8][64]  g_proj partials
#define WS_PGG    118912        // [32][8]      gamma_tri partials
#define WS_GL     131072        // [8][NV] gamma-folded group logits

// =====================================================================
// kA: 57 blocks.
//   0..7   : Gauss-Jordan (I-A)Q=(I+A) per batch (+ htr write)
//   8      : S = WG Sigma WG^T, tvec, c0
//   9..24  : h-GEMV partials (WQ/hlie/wgamma read ONCE)
//   25..56 : gdown partials (gdown read ONCE)
// =====================================================================
__global__ __launch_bounds__(256) void kA_prep(
    const float* __restrict__ h_t, const float* __restrict__ A_t,
    const float* __restrict__ WG_w, const float* __restrict__ WG_b,
    const float* __restrict__ Sigma_inv,
    const float* __restrict__ WQ_w, const float* __restrict__ wgamma_w,
    const float* __restrict__ hlie_w, const float* __restrict__ gdown_w,
    float* __restrict__ ws)
{
    __shared__ float Ash[64][65];
    __shared__ float Gsh[64][65];
    __shared__ float hsh[1024];
    __shared__ float piv[2][132];
    __shared__ float fr[2][64];
    __shared__ float dsh[64];

    const int tid = threadIdx.x;
    const int blk = blockIdx.x;

    if (blk < 8) {
        // ---------- Gauss-Jordan ----------
        const int b  = blk;
        const int i  = tid & 63;
        const int cb = __builtin_amdgcn_readfirstlane(tid >> 6);

        for (int idx = tid; idx < 4096; idx += 256)
            Ash[idx >> 6][idx & 63] = A_t[b*4096 + idx];
        for (int k = tid; k < 1024; k += 256)
            ws[WS_HTR + k*8 + b] = h_t[b*1024 + k];
        __syncthreads();

        float w[32];
        if (cb < 2) {
            #pragma unroll
            for (int jj = 0; jj < 32; ++jj) {
                int j = cb*32 + jj;
                w[jj] = (i == j ? 1.0f : 0.0f) - Ash[i][j];
            }
        } else {
            #pragma unroll
            for (int jj = 0; jj < 32; ++jj) {
                int j = (cb - 2)*32 + jj;
                w[jj] = (i == j ? 1.0f : 0.0f) + Ash[i][j];
            }
        }
        __syncthreads();

        #pragma unroll
        for (int k = 0; k < 64; ++k) {
            const int kb  = k >> 5;
            const int sel = k & 1;
            if (cb == kb) fr[sel][i] = w[k & 31];
            if (i == k) {
                #pragma unroll
                for (int q4 = 0; q4 < 8; ++q4)
                    *(float4*)&piv[sel][cb*32 + q4*4] =
                        make_float4(w[q4*4], w[q4*4+1], w[q4*4+2], w[q4*4+3]);
            }
            __syncthreads();
            float pk = piv[sel][k];
            float f = (i == k) ? 0.0f : (fr[sel][i] / pk);
            #pragma unroll
            for (int jj = 0; jj < 32; ++jj)
                w[jj] -= f * piv[sel][cb*32 + jj];
        }

        if (cb == (i >> 5)) dsh[i] = w[i & 31];
        __syncthreads();
        if (cb >= 2) {
            float dinv = 1.0f / dsh[i];
            #pragma unroll
            for (int jj = 0; jj < 32; ++jj)
                Ash[i][(cb - 2)*32 + jj] = w[jj] * dinv;   // Ash := Q
        }
        __syncthreads();
        for (int idx = tid; idx < 4096; idx += 256)
            ws[WS_Q + b*4096 + idx] = Ash[idx >> 6][idx & 63];
        return;
    }

    if (blk == 8) {
        // ---------- S = WG Sigma WG^T, tvec, c0 ----------
        const int a   = tid & 63;
        const int cb8 = __builtin_amdgcn_readfirstlane(tid >> 6);
        float* sig = hsh;
        float* bg  = hsh + 64;
        if (tid < 64) { sig[tid] = Sigma_inv[tid]; bg[tid] = WG_b[tid]; }
        __syncthreads();
        for (int idx = tid; idx < 4096; idx += 256) {
            int r = idx >> 6, c = idx & 63;
            float wv = WG_w[idx];
            Gsh[r][c] = wv;            // Wr
            Ash[r][c] = wv * sig[c];   // Wsc
        }
        __syncthreads();
        float t8[16];
        #pragma unroll
        for (int j = 0; j < 16; ++j) t8[j] = 0.0f;
        for (int p = 0; p < 64; ++p) {
            float wv = Ash[a][p];
            #pragma unroll
            for (int jj = 0; jj < 16; ++jj) t8[jj] = fmaf(wv, Gsh[cb8*16 + jj][p], t8[jj]);
        }
        #pragma unroll
        for (int jj = 0; jj < 16; ++jj)
            ws[WS_S + a*64 + cb8*16 + jj] = t8[jj];
        if (cb8 == 0) {
            float s = 0.0f;
            for (int p = 0; p < 64; ++p) s += Ash[a][p] * bg[p];
            ws[WS_TV + a] = 2.0f * s;
        }
        if (tid == 0) {
            float c0 = 0.0f;
            for (int p = 0; p < 64; ++p) c0 += sig[p] * bg[p] * bg[p];
            ws[WS_C0] = c0;
        }
        return;
    }

    if (blk < 25) {
        // ---------- h-GEMV partials, chunk c ----------
        const int c = blk - 9;
        const int i = tid & 63;
        const int w = __builtin_amdgcn_readfirstlane(tid >> 6);
        for (int idx = tid; idx < 4096; idx += 256) {
            int r = idx >> 6, col = idx & 63;
            int krow = c*64 + r;
            Ash[r][col] = WQ_w[krow*64 + col];
            Gsh[r][col] = hlie_w[krow*64 + col];
        }
        for (int t = tid; t < 512; t += 256) {
            int b = t >> 6, kk = t & 63;
            hsh[b*64 + kk] = h_t[b*1024 + c*64 + kk];
        }
        if (tid < 64) dsh[tid] = wgamma_w[c*64 + tid];
        __syncthreads();
        const int b0 = 2*w, b1 = 2*w + 1;
        float q0 = 0, q1 = 0, l0 = 0, l1 = 0;
        #pragma unroll 8
        for (int kk = 0; kk < 64; ++kk) {
            float a = Ash[kk][i], g = Gsh[kk][i];
            float h0 = hsh[b0*64 + kk], h1 = hsh[b1*64 + kk];
            q0 = fmaf(h0, a, q0); q1 = fmaf(h1, a, q1);
            l0 = fmaf(h0, g, l0); l1 = fmaf(h1, g, l1);
        }
        ws[WS_PQT + (c*8 + b0)*64 + i] = q0;
        ws[WS_PQT + (c*8 + b1)*64 + i] = q1;
        ws[WS_PHL + (c*8 + b0)*64 + i] = l0;
        ws[WS_PHL + (c*8 + b1)*64 + i] = l1;
        float g0 = hsh[b0*64 + i] * dsh[i];
        float g1 = hsh[b1*64 + i] * dsh[i];
        #pragma unroll
        for (int off = 32; off > 0; off >>= 1) {
            g0 += __shfl_xor(g0, off);
            g1 += __shfl_xor(g1, off);
        }
        if (i == 0) {
            ws[WS_PGH + c*8 + b0] = g0;
            ws[WS_PGH + c*8 + b1] = g1;
        }
        return;
    }

    // ---------- gdown partials, chunk c ----------
    {
        const int c = blk - 25;
        const int i = tid & 63;
        const int w = __builtin_amdgcn_readfirstlane(tid >> 6);
        for (int idx = tid; idx < 4032; idx += 256) {
            int r = idx >> 6, col = idx & 63;
            Ash[r][col] = gdown_w[(c*63 + r)*64 + col];
        }
        for (int t = tid; t < 504; t += 256) {
            int b = t / 63, sl = t % 63;
            int s = c*63 + sl;
            int i2 = 0, f = 0;
            while (f + (63 - i2) <= s) { f += 63 - i2; ++i2; }
            int j2 = i2 + 1 + (s - f);
            hsh[b*63 + sl] = A_t[b*4096 + i2*64 + j2];
        }
        if (tid < 63) dsh[tid] = wgamma_w[1088 + c*63 + tid];
        __syncthreads();
        const int b0 = 2*w, b1 = 2*w + 1;
        float a0 = 0, a1 = 0;
        #pragma unroll 4
        for (int sl = 0; sl < 63; ++sl) {
            float gd = Ash[sl][i];
            a0 = fmaf(hsh[b0*63 + sl], gd, a0);
            a1 = fmaf(hsh[b1*63 + sl], gd, a1);
        }
        ws[WS_PGP + (c*8 + b0)*64 + i] = a0;
        ws[WS_PGP + (c*8 + b1)*64 + i] = a1;
        float g0 = (i < 63) ? hsh[b0*63 + i] * dsh[i] : 0.0f;
        float g1 = (i < 63) ? hsh[b1*63 + i] * dsh[i] : 0.0f;
        #pragma unroll
        for (int off = 32; off > 0; off >>= 1) {
            g0 += __shfl_xor(g0, off);
            g1 += __shfl_xor(g1, off);
        }
        if (i == 0) {
            ws[WS_PGG + c*8 + b0] = g0;
            ws[WS_PGG + c*8 + b1] = g1;
        }
    }
}

// =====================================================================
// kB: 8 blocks, per batch: reduce h-GEMV partials -> qt, hl, gamma_h;
//     chain qkv -> ghl -> v0 -> w1; W = Q G Q^T -> ws.
// =====================================================================
__global__ __launch_bounds__(256) void kB_chain(
    const float* __restrict__ G_t,
    const float* __restrict__ WQ_b, const float* __restrict__ WK_w,
    const float* __restrict__ hlie_b,
    float* __restrict__ ws)
{
    __shared__ float Qsh[64][65], Gsh[64][65];
    __shared__ float part[4][64], partb[4][64];
    __shared__ float qt[64], hl[64], qkv[64], v0[64];
    __shared__ float red16[16];

    const int b = blockIdx.x, tid = threadIdx.x;
    const int i = tid & 63;
    const int cb = __builtin_amdgcn_readfirstlane(tid >> 6);
    const int col0 = cb * 16;

    for (int idx = tid; idx < 4096; idx += 256) {
        int r = idx >> 6, c = idx & 63;
        Qsh[r][c] = ws[WS_Q + b*4096 + idx];
        Gsh[r][c] = G_t[b*4096 + idx];
    }
    {
        float aq = 0, ah = 0;
        #pragma unroll
        for (int cc = 0; cc < 4; ++cc) {
            int c = cb*4 + cc;
            aq += ws[WS_PQT + (c*8 + b)*64 + i];
            ah += ws[WS_PHL + (c*8 + b)*64 + i];
        }
        part[cb][i] = aq; partb[cb][i] = ah;
    }
    if (tid < 16) red16[tid] = ws[WS_PGH + tid*8 + b];
    __syncthreads();
    if (tid < 64) {
        qt[tid] = part[0][tid]+part[1][tid]+part[2][tid]+part[3][tid] + WQ_b[tid];
        hl[tid] = partb[0][tid]+partb[1][tid]+partb[2][tid]+partb[3][tid] + hlie_b[tid];
    }
    if (tid == 0) {
        float s = 0;
        #pragma unroll
        for (int j = 0; j < 16; ++j) s += red16[j];
        ws[WS_GH + b] = s;
    }
    __syncthreads();
    {
        float acc = 0;
        #pragma unroll
        for (int jj = 0; jj < 16; ++jj)
            acc = fmaf(WK_w[i*64 + col0 + jj], qt[col0 + jj], acc);
        part[cb][i] = acc;
    }
    __syncthreads();
    if (tid < 64) qkv[tid] = part[0][tid]+part[1][tid]+part[2][tid]+part[3][tid];
    __syncthreads();
    {
        float acc = 0;
        #pragma unroll
        for (int jj = 0; jj < 16; ++jj)
            acc = fmaf(Gsh[i][col0 + jj], hl[col0 + jj], acc);
        part[cb][i] = acc;
    }
    __syncthreads();
    if (tid < 64)
        v0[tid] = SCALE*qkv[tid] + part[0][tid]+part[1][tid]+part[2][tid]+part[3][tid];
    __syncthreads();
    {
        float acc = 0;
        #pragma unroll
        for (int jj = 0; jj < 16; ++jj)
            acc = fmaf(Qsh[i][col0 + jj], v0[col0 + jj], acc);
        part[cb][i] = acc;
    }
    __syncthreads();
    if (tid < 64) {
        ws[WS_W1 + b*64 + tid]   = part[0][tid]+part[1][tid]+part[2][tid]+part[3][tid];
        ws[WS_HLIE + b*64 + tid] = hl[tid];
    }
    float tt[16];
    #pragma unroll
    for (int j = 0; j < 16; ++j) tt[j] = 0;
    for (int r = 0; r < 64; ++r) {
        float qv = Qsh[i][r];
        #pragma unroll
        for (int j = 0; j < 16; ++j) tt[j] = fmaf(qv, Gsh[r][col0 + j], tt[j]);
    }
    __syncthreads();
    #pragma unroll
    for (int j = 0; j < 16; ++j) Gsh[i][col0 + j] = tt[j];   // Gsh := T
    __syncthreads();
    float w2r[16];
    #pragma unroll
    for (int j = 0; j < 16; ++j) w2r[j] = 0;
    for (int q = 0; q < 64; ++q) {
        float tv = Gsh[i][q];
        #pragma unroll
        for (int j = 0; j < 16; ++j) w2r[j] = fmaf(tv, Qsh[col0 + j][q], w2r[j]);
    }
    #pragma unroll
    for (int j = 0; j < 16; ++j)
        ws[WS_WMAT + b*4096 + (col0 + j)*64 + i] = w2r[j];
}

// =====================================================================
// kC: 32 blocks = (b, quarter). scores via b W b^T from LDS.
// =====================================================================
__global__ __launch_bounds__(256) void kC_scores(
    const float* __restrict__ B_t, float* __restrict__ ws)
{
    __shared__ float Bsh[64][65];
    __shared__ float Wsh[64][64];
    __shared__ float w1sh[64];
    __shared__ float part[4][64];
    const int b = blockIdx.x >> 2, q4 = blockIdx.x & 3;
    const int tid = threadIdx.x, lane = tid & 63;
    const int gu = __builtin_amdgcn_readfirstlane(tid >> 6);
    const int col0 = gu * 16;
    for (int idx = tid; idx < 4096; idx += 256) {
        int r = idx >> 6, c = idx & 63;
        Bsh[r][c] = B_t[b*16384 + (q4*64 + r)*64 + c];
        Wsh[r][c] = ws[WS_WMAT + b*4096 + idx];
    }
    if (tid < 64) w1sh[tid] = ws[WS_W1 + b*64 + tid];
    __syncthreads();
    float t[16];
    #pragma unroll
    for (int j = 0; j < 16; ++j) t[j] = 0;
    for (int p = 0; p < 64; ++p) {
        float bv = Bsh[lane][p];
        #pragma unroll
        for (int j = 0; j < 16; ++j) t[j] = fmaf(bv, Wsh[p][col0 + j], t[j]);
    }
    float ps = 0;
    #pragma unroll
    for (int j = 0; j < 16; ++j) ps += (w1sh[col0+j] - 0.5f*t[j]) * Bsh[lane][col0+j];
    part[gu][lane] = ps;
    __syncthreads();
    if (tid < 64)
        ws[WS_SC + b*256 + q4*64 + tid] =
            part[0][tid]+part[1][tid]+part[2][tid]+part[3][tid];
}

// =====================================================================
// kD: per batch: softmax(alpha), c chain, g_proj (partial reduce),
//     gamma, w_b.
// =====================================================================
__global__ __launch_bounds__(256) void kD_mid(
    const float* __restrict__ B_t,
    const float* __restrict__ WV_w, const float* __restrict__ WV_b,
    const float* __restrict__ WC_w, const float* __restrict__ WC_b,
    const float* __restrict__ WG_w, const float* __restrict__ WG_b,
    const float* __restrict__ wgamma_w, const float* __restrict__ wgamma_b,
    const float* __restrict__ Sigma_inv,
    float* __restrict__ ws)
{
    __shared__ float alpha[256], rr[256];
    __shared__ float part[4][64];
    __shared__ float cBr[64], cB[64], ct[64], cw[64], crot[64], gp[64], uv[64];
    __shared__ float red32[32];
    const int b = blockIdx.x, tid = threadIdx.x, lane = tid & 63;
    const int gu = __builtin_amdgcn_readfirstlane(tid >> 6);
    const int col0 = gu * 16;
    const float* Qb = ws + WS_Q + b*4096;

    float sv = ws[WS_SC + b*256 + tid];
    rr[tid] = sv;
    if (tid < 32) red32[tid] = ws[WS_PGG + tid*8 + b];
    __syncthreads();
    for (int off = 128; off > 0; off >>= 1) { if (tid < off) rr[tid] = fmaxf(rr[tid], rr[tid+off]); __syncthreads(); }
    float smax = rr[0]; __syncthreads();
    float e = expf(sv - smax);
    rr[tid] = e; __syncthreads();
    for (int off = 128; off > 0; off >>= 1) { if (tid < off) rr[tid] += rr[tid+off]; __syncthreads(); }
    float den = rr[0]; __syncthreads();
    alpha[tid] = e / den;
    __syncthreads();
    {
        float acc = 0;
        for (int nn = 0; nn < 64; ++nn) {
            int n = gu*64 + nn;
            acc = fmaf(alpha[n], B_t[b*16384 + n*64 + lane], acc);
        }
        part[gu][lane] = acc;
    }
    __syncthreads();
    if (tid < 64) cBr[tid] = part[0][tid]+part[1][tid]+part[2][tid]+part[3][tid];
    __syncthreads();
    {
        float acc = 0;
        #pragma unroll
        for (int pp = 0; pp < 16; ++pp) { int p = col0+pp; acc = fmaf(cBr[p], Qb[p*64+lane], acc); }
        part[gu][lane] = acc;
    }
    __syncthreads();
    if (tid < 64) cB[tid] = part[0][tid]+part[1][tid]+part[2][tid]+part[3][tid];
    __syncthreads();
    {
        float acc = 0;
        #pragma unroll
        for (int pp = 0; pp < 16; ++pp) { int p = col0+pp; acc = fmaf(cB[p], WV_w[p*64+lane], acc); }
        part[gu][lane] = acc;
    }
    __syncthreads();
    if (tid < 64) {
        float v = part[0][tid]+part[1][tid]+part[2][tid]+part[3][tid] + WV_b[tid];
        ct[tid] = v; ws[WS_CT + b*64 + tid] = v;
    }
    __syncthreads();
    {
        float acc = 0;
        #pragma unroll
        for (int pp = 0; pp < 16; ++pp) { int p = col0+pp; acc = fmaf(ct[p], WC_w[p*64+lane], acc); }
        part[gu][lane] = acc;
    }
    __syncthreads();
    if (tid < 64) cw[tid] = part[0][tid]+part[1][tid]+part[2][tid]+part[3][tid] + WC_b[tid];
    __syncthreads();
    {
        float acc = 0;
        #pragma unroll
        for (int pp = 0; pp < 16; ++pp) { int p = col0+pp; acc = fmaf(cw[p], Qb[p*64+lane], acc); }
        part[gu][lane] = acc;
    }
    __syncthreads();
    if (tid < 64) crot[tid] = part[0][tid]+part[1][tid]+part[2][tid]+part[3][tid];
    __syncthreads();
    {
        float acc = 0;
        #pragma unroll
        for (int cc = 0; cc < 8; ++cc) {
            int c = gu*8 + cc;
            acc += ws[WS_PGP + (c*8 + b)*64 + lane];
        }
        part[gu][lane] = acc;
    }
    if (tid < 64) rr[64 + tid] = ct[tid] * wgamma_w[1024 + tid];
    __syncthreads();
    if (tid < 64) {
        float g = part[0][tid]+part[1][tid]+part[2][tid]+part[3][tid];
        gp[tid] = g; uv[tid] = 2.0f * Sigma_inv[tid] * g;
    }
    if (tid == 0) {
        float gc = 0;
        for (int j = 0; j < 64; ++j) gc += rr[64 + j];
        float ga = 0;
        for (int j = 0; j < 32; ++j) ga += red32[j];
        float z = ws[WS_GH + b] + gc + ga + wgamma_b[0];
        ws[WS_GAMMA + b] = 1.0f / (1.0f + expf(-z));
    }
    __syncthreads();
    {
        float acc = 0;
        #pragma unroll
        for (int pp = 0; pp < 16; ++pp) { int p = col0+pp; acc = fmaf(WG_w[lane*64+p], uv[p], acc); }
        part[gu][lane] = acc;
    }
    if (tid < 64) rr[tid] = WG_b[tid]*uv[tid] - gp[tid]*gp[tid]*Sigma_inv[tid];
    __syncthreads();
    if (tid < 64)
        ws[WS_WB + b*64 + tid] = SCALE*crot[tid]
            + part[0][tid]+part[1][tid]+part[2][tid]+part[3][tid];
    if (tid == 0) { float s = 0; for (int j = 0; j < 64; ++j) s += rr[j]; ws[WS_CONSTB + b] = s; }
}

// =====================================================================
// k5a: group-logit side. 393 blocks x 256 thr, 128 v/block (2 thr/v).
//      E read once; writes gl[b][v] = gamma_b*(gd + const_b - sv) to ws.
// =====================================================================
__global__ __launch_bounds__(256) void k5a_group(
    const float* __restrict__ E, float* __restrict__ ws)
{
    __shared__ float smem[14544];   // 58.2 KB
    const int tid  = threadIdx.x;
    const int half = tid >> 7;
    const int vt   = tid & 127;
    const int vb = blockIdx.x * 128;
    const int v = vb + vt;
    const bool vok = v < NV;

    float* Esh  = smem;            // [128][66]
    float* Ssh  = smem + 8448;     // [64][64]
    float* tvsh = smem + 12544;    // [64]
    float* wbsh = smem + 12608;    // [8][64]
    float* gmsh = smem + 13120;    // [8]
    float* cbsh = smem + 13128;    // [8]
    float* svsh = smem + 13136;    // [2][128]
    float* gdsh = smem + 13392;    // [128][9]

    for (int idx = tid; idx < 2048; idx += 256) {
        int r = idx >> 4, c4 = (idx & 15) * 4;
        int vr = vb + r; if (vr >= NV) vr = NV - 1;
        float4 e4 = *(const float4*)(E + (size_t)vr * 64 + c4);
        float* dst = Esh + r*66 + c4;
        dst[0] = e4.x; dst[1] = e4.y; dst[2] = e4.z; dst[3] = e4.w;
    }
    for (int idx = tid; idx < 4096; idx += 256) Ssh[idx] = ws[WS_S + idx];
    for (int idx = tid; idx < 512; idx += 256) wbsh[idx] = ws[WS_WB + idx];
    if (tid < 64) tvsh[tid] = ws[WS_TV + tid];
    if (tid < 8) { gmsh[tid] = ws[WS_GAMMA + tid]; cbsh[tid] = ws[WS_CONSTB + tid]; }
    __syncthreads();
    {
        const float* er = Esh + vt*66;
        float sv = (half == 0) ? ws[WS_C0] : 0.0f;
        #pragma unroll
        for (int jj = 0; jj < 2; ++jj) {
            const int jb = half*2 + jj;
            float t[16];
            #pragma unroll
            for (int j = 0; j < 16; ++j) t[j] = 0.0f;
            for (int p = 0; p < 64; ++p) {
                float ep = er[p];
                #pragma unroll
                for (int j = 0; j < 16; ++j)
                    t[j] = fmaf(ep, Ssh[p*64 + jb*16 + j], t[j]);
            }
            #pragma unroll
            for (int j = 0; j < 16; ++j)
                sv += (t[j] + tvsh[jb*16 + j]) * er[jb*16 + j];
        }
        svsh[half*128 + vt] = sv;
        const float* w0 = wbsh + (half*4    )*64;
        const float* w1 = wbsh + (half*4 + 1)*64;
        const float* w2 = wbsh + (half*4 + 2)*64;
        const float* w3 = wbsh + (half*4 + 3)*64;
        float g0 = 0, g1 = 0, g2 = 0, g3 = 0;
        #pragma unroll 8
        for (int p = 0; p < 64; ++p) {
            float ep = er[p];
            g0 = fmaf(ep, w0[p], g0); g1 = fmaf(ep, w1[p], g1);
            g2 = fmaf(ep, w2[p], g2); g3 = fmaf(ep, w3[p], g3);
        }
        float* gr = gdsh + vt*9 + half*4;
        gr[0] = g0; gr[1] = g1; gr[2] = g2; gr[3] = g3;
    }
    __syncthreads();
    if (half == 0 && vok) {
        float svt = svsh[vt] + svsh[128 + vt];
        const float* gr = gdsh + vt*9;
        #pragma unroll
        for (int bb = 0; bb < 8; ++bb)
            ws[WS_GL + bb*NV + v] = gmsh[bb] * (gr[bb] + cbsh[bb] - svt);
    }
}

// =====================================================================
// k5b: pure WO stream. 1571 blocks x 256 thr, 32 v/block, 8-way k-split.
//      LDS 33 KB only -> ~4-5 blocks/CU: latency hidden.
//      out[b][v] = sum_k h[k][b]*WO[k][v] + gl[b][v].
// =====================================================================
#define KU5 16
__global__ __launch_bounds__(256, 4) void k5b_wo(
    const float* __restrict__ WO_w,
    const float* __restrict__ ws, float* __restrict__ out)
{
    __shared__ float hsh[8192];     // [1024][8]; tail reused as reduce buf
    const int tid = threadIdx.x;
    const int vt  = tid & 31;
    const int kg  = tid >> 5;       // 0..7
    const int vb  = blockIdx.x * 32;
    const int v   = vb + vt;
    const bool vok = v < NV;
    const int vv = vok ? v : NV - 1;

    for (int idx = tid; idx < 2048; idx += 256)
        *(float4*)(hsh + idx*4) = *(const float4*)(ws + WS_HTR + idx*4);
    __syncthreads();

    float acc[8];
    #pragma unroll
    for (int bb = 0; bb < 8; ++bb) acc[bb] = 0.0f;
    {
        const float* wo = WO_w + (size_t)(kg * 128) * NV + vv;
        const float* hb = hsh + kg*128*8;
        for (int k0 = 0; k0 < 128; k0 += KU5) {
            float wr[KU5];
            #pragma unroll
            for (int u = 0; u < KU5; ++u) wr[u] = wo[(size_t)(k0 + u) * NV];
            #pragma unroll
            for (int u = 0; u < KU5; ++u) {
                const float* hp = hb + (k0 + u)*8;
                #pragma unroll
                for (int bb = 0; bb < 8; ++bb) acc[bb] = fmaf(hp[bb], wr[u], acc[bb]);
            }
        }
    }
    // prefetch gl for the combining threads (hidden under reduction)
    float gl[8];
    if (kg == 0) {
        #pragma unroll
        for (int bb = 0; bb < 8; ++bb) gl[bb] = ws[WS_GL + bb*NV + vv];
    }
    __syncthreads();               // all hsh reads done; reuse as reduce buf
    float* red = hsh;              // [4][32][8]
    if (kg >= 4) {
        float* r = red + ((kg - 4)*32 + vt)*8;
        #pragma unroll
        for (int bb = 0; bb < 8; ++bb) r[bb] = acc[bb];
    }
    __syncthreads();
    if (kg < 4) {
        const float* r = red + (kg*32 + vt)*8;
        #pragma unroll
        for (int bb = 0; bb < 8; ++bb) acc[bb] += r[bb];
    }
    __syncthreads();
    if (kg >= 2 && kg < 4) {
        float* r = red + ((kg - 2)*32 + vt)*8;
        #pragma unroll
        for (int bb = 0; bb < 8; ++bb) r[bb] = acc[bb];
    }
    __syncthreads();
    if (kg < 2) {
        const float* r = red + (kg*32 + vt)*8;
        #pragma unroll
        for (int bb = 0; bb < 8; ++bb) acc[bb] += r[bb];
    }
    __syncthreads();
    if (kg == 1) {
        float* r = red + vt*8;
        #pragma unroll
        for (int bb = 0; bb < 8; ++bb) r[bb] = acc[bb];
    }
    __syncthreads();
    if (kg == 0 && vok) {
        const float* r = red + vt*8;
        #pragma unroll
        for (int bb = 0; bb < 8; ++bb)
            out[bb*NV + v] = acc[bb] + r[bb] + gl[bb];
    }
}

// =====================================================================
// K6a: 32 blocks = (b, quarter). Single pass: per-thread top-8 + online
// (m,s1,s2); wave shfl extraction; 4-list merge; shfl sum reduce.
// =====================================================================
#define NQ 12565
__global__ __launch_bounds__(256) void k6a_scan(
    const float* __restrict__ outl, float* __restrict__ ws)
{
    __shared__ float mvw[4][8];
    __shared__ int   miw[4][8];
    __shared__ float t8v[8];
    __shared__ int   t8i[8];
    __shared__ float redv[4], sred[4];
    const int b = blockIdx.x >> 2, qq = blockIdx.x & 3;
    const int tid = threadIdx.x, lane = tid & 63, wvi = tid >> 6;
    const int v0 = qq * NQ;
    const int v1 = (v0 + NQ < NV) ? (v0 + NQ) : NV;
    const float* lg = outl + b*NV;

    float lv[8]; int li[8];
    #pragma unroll
    for (int u = 0; u < 8; ++u) { lv[u] = -INFINITY; li[u] = 0x7fffffff; }
    float mt = -INFINITY, s1 = 0.0f, s2 = 0.0f;
    for (int v = v0 + tid; v < v1; v += 256) {
        float x = lg[v];
        if (x > mt) {
            float r = expf(mt - x);
            s1 *= r; s2 *= r; mt = x;
        }
        float ee = expf(x - mt);
        s1 += ee; s2 += x * ee;
        if (x > lv[7]) {
            float cv = x; int ci = v;
            #pragma unroll
            for (int u = 0; u < 8; ++u) {
                if (cv > lv[u]) {
                    float tv = lv[u]; lv[u] = cv; cv = tv;
                    int   ti = li[u]; li[u] = ci; ci = ti;
                }
            }
        }
    }
    float wv8[8]; int wi8[8];
    #pragma unroll
    for (int it = 0; it < 8; ++it) {
        float bv = lv[0]; int bi = li[0];
        #pragma unroll
        for (int off = 32; off > 0; off >>= 1) {
            float ov = __shfl_xor(bv, off);
            int   oi = __shfl_xor(bi, off);
            if (ov > bv || (ov == bv && oi < bi)) { bv = ov; bi = oi; }
        }
        wv8[it] = bv; wi8[it] = bi;
        if (lv[0] == bv && li[0] == bi) {
            lv[0]=lv[1]; lv[1]=lv[2]; lv[2]=lv[3]; lv[3]=lv[4];
            lv[4]=lv[5]; lv[5]=lv[6]; lv[6]=lv[7]; lv[7]=-INFINITY;
            li[0]=li[1]; li[1]=li[2]; li[2]=li[3]; li[3]=li[4];
            li[4]=li[5]; li[5]=li[6]; li[6]=li[7]; li[7]=0x7fffffff;
        }
    }
    if (lane == 0) {
        #pragma unroll
        for (int u = 0; u < 8; ++u) { mvw[wvi][u] = wv8[u]; miw[wvi][u] = wi8[u]; }
    }
    __syncthreads();
    if (tid == 0) {
        int pA = 0, pB = 0, pC = 0, pD = 0;
        for (int it = 0; it < 8; ++it) {
            float vA = mvw[0][pA], vB = mvw[1][pB], vC = mvw[2][pC], vD = mvw[3][pD];
            int   iA = miw[0][pA], iB = miw[1][pB], iC = miw[2][pC], iD = miw[3][pD];
            float best = vA; int bi = iA; int w = 0;
            if (vB > best || (vB == best && iB < bi)) { best = vB; bi = iB; w = 1; }
            if (vC > best || (vC == best && iC < bi)) { best = vC; bi = iC; w = 2; }
            if (vD > best || (vD == best && iD < bi)) { best = vD; bi = iD; w = 3; }
            t8v[it] = best; t8i[it] = bi;
            if (w == 0) ++pA; else if (w == 1) ++pB; else if (w == 2) ++pC; else ++pD;
        }
    }
    __syncthreads();
    float Mp = t8v[0];
    {
        float r = expf(mt - Mp);
        s1 *= r; s2 *= r;
    }
    #pragma unroll
    for (int off = 32; off > 0; off >>= 1) {
        s1 += __shfl_xor(s1, off);
        s2 += __shfl_xor(s2, off);
    }
    if (lane == 0) { redv[wvi] = s1; sred[wvi] = s2; }
    __syncthreads();
    if (tid == 0) {
        int base = WS_P6 + (b*4 + qq)*20;
        #pragma unroll
        for (int u = 0; u < 8; ++u) { ws[base + u] = t8v[u]; ((int*)ws)[base + 8 + u] = t8i[u]; }
        ws[base + 16] = Mp;
        ws[base + 17] = redv[0]+redv[1]+redv[2]+redv[3];
        ws[base + 18] = sred[0]+sred[1]+sred[2]+sred[3];
    }
}

// =====================================================================
// K6b: per batch: merge partials, H, E_exp, rho, mu, m_next, A_next
// =====================================================================
__global__ __launch_bounds__(256) void k6b_final(
    const float* __restrict__ h_t, const float* __restrict__ A_t,
    const float* __restrict__ E, const float* __restrict__ e_mask,
    const float* __restrict__ G_t,
    const float* __restrict__ wmu_w, const float* __restrict__ wmu_b,
    const float* __restrict__ ws, float* __restrict__ out)
{
    __shared__ float mv[32];
    __shared__ int   mi[32];
    __shared__ float t8v[8];
    __shared__ int   t8i[8];
    __shared__ float toppsh[8];
    __shared__ float redv[256];
    __shared__ float uvec[64], eexp[64], msh[64], emsh[64];
    __shared__ float scal[4];
    const int b = blockIdx.x, tid = threadIdx.x;

    if (tid < 32) {
        int base = WS_P6 + (b*4 + (tid >> 3))*20;
        mv[tid] = ws[base + (tid & 7)];
        mi[tid] = ((const int*)ws)[base + 8 + (tid & 7)];
    }
    __syncthreads();
    if (tid == 0) {
        unsigned used = 0;
        for (int it = 0; it < 8; ++it) {
            float best = -INFINITY; int bi = 0x7fffffff, bs = 0;
            for (int c = 0; c < 32; ++c) {
                if (used & (1u << c)) continue;
                float x = mv[c];
                if (x > best || (x == best && mi[c] < bi)) { best = x; bi = mi[c]; bs = c; }
            }
            used |= 1u << bs; t8v[it] = best; t8i[it] = bi;
        }
        float M = t8v[0];
        float s1 = 0, s2 = 0;
        for (int q = 0; q < 4; ++q) {
            int base = WS_P6 + (b*4 + q)*20;
            float sc_ = expf(ws[base + 16] - M);
            s1 += ws[base + 17] * sc_; s2 += ws[base + 18] * sc_;
        }
        scal[0] = M + logf(s1) - s2 / s1;       // H
        float ts = 0, tv_[8];
        #pragma unroll
        for (int u = 0; u < 8; ++u) { tv_[u] = expf(t8v[u] - M); ts += tv_[u]; }
        #pragma unroll
        for (int u = 0; u < 8; ++u) toppsh[u] = tv_[u] / ts;
    }
    __syncthreads();
    if (tid < 64) {
        float u_ = 0;
        #pragma unroll
        for (int j = 0; j < 8; ++j) u_ += toppsh[j] * E[t8i[j]*64 + tid];
        uvec[tid] = u_;
    }
    __syncthreads();
    if (tid < 64) {
        const float* Qb = ws + WS_Q + b*4096;
        float a = 0;
        for (int p = 0; p < 64; ++p) a += uvec[p] * Qb[p*64 + tid];
        eexp[tid] = a;
    }
    __syncthreads();
    {   // rho
        const float* Gb = G_t + b*4096;
        const float* HL = ws + WS_HLIE + b*64;
        float a = 0;
        #pragma unroll 4
        for (int t2 = 0; t2 < 16; ++t2) {
            int idx = tid*16 + t2;
            int p = idx >> 6, q = idx & 63;
            a += (eexp[p] - HL[p]) * Gb[idx] * (eexp[q] - HL[q]);
        }
        redv[tid] = a;
    }
    __syncthreads();
    for (int off = 128; off > 0; off >>= 1) {
        if (tid < off) redv[tid] += redv[tid + off];
        __syncthreads();
    }
    if (tid == 0) scal[1] = redv[0];
    __syncthreads();
    // mu
    float pm = 0;
    for (int k = tid; k < 1024; k += 256) pm += h_t[b*1024 + k] * wmu_w[k];
    if (tid < 64) pm += ws[WS_CT + b*64 + tid] * wmu_w[1024 + tid];
    redv[tid] = pm;
    __syncthreads();
    for (int off = 128; off > 0; off >>= 1) {
        if (tid < off) redv[tid] += redv[tid + off];
        __syncthreads();
    }
    if (tid == 0) {
        float z = redv[0] + scal[0]*wmu_w[1088] + scal[1]*wmu_w[1089] + wmu_b[0];
        scal[2] = 1.0f / (1.0f + expf(-z));
    }
    __syncthreads();
    if (tid < 64) {
        float mu = scal[2];
        float em = e_mask[b*64 + tid];
        float m = mu*em + (1.0f - mu)*eexp[tid];
        out[OUT_M + b*64 + tid] = m;
        msh[tid] = m; emsh[tid] = em;
    }
    __syncthreads();
    for (int idx = tid; idx < 4096; idx += 256) {
        int i = idx >> 6, j = idx & 63;
        out[OUT_A + b*4096 + idx] = A_t[b*4096 + idx]
            + 0.1f*(msh[i]*emsh[j] - msh[j]*emsh[i]);
    }
}

// =====================================================================
extern "C" void kernel_launch(void* const* d_in, const int* in_sizes, int n_in,
                              void* d_out, int out_size, void* d_ws, size_t ws_size,
                              hipStream_t stream)
{
    const float* h_t      = (const float*)d_in[0];
    const float* A_t      = (const float*)d_in[1];
    const float* B_t      = (const float*)d_in[2];
    const float* E        = (const float*)d_in[3];
    const float* e_mask   = (const float*)d_in[4];
    const float* G_t      = (const float*)d_in[5];
    const float* WQ_w     = (const float*)d_in[7];
    const float* WQ_b     = (const float*)d_in[8];
    const float* WK_w     = (const float*)d_in[9];
    const float* WV_w     = (const float*)d_in[11];
    const float* WV_b     = (const float*)d_in[12];
    const float* WC_w     = (const float*)d_in[13];
    const float* WC_b     = (const float*)d_in[14];
    const float* WO_w     = (const float*)d_in[15];
    const float* WG_w     = (const float*)d_in[16];
    const float* WG_b     = (const float*)d_in[17];
    const float* wgamma_w = (const float*)d_in[18];
    const float* wgamma_b = (const float*)d_in[19];
    const float* wmu_w    = (const float*)d_in[20];
    const float* wmu_b    = (const float*)d_in[21];
    const float* gdown_w  = (const float*)d_in[22];
    const float* Sigma_inv= (const float*)d_in[23];
    const float* hlie_w   = (const float*)d_in[24];
    const float* hlie_b   = (const float*)d_in[25];
    float* out = (float*)d_out;
    float* ws  = (float*)d_ws;

    kA_prep<<<57, 256, 0, stream>>>(h_t, A_t, WG_w, WG_b, Sigma_inv,
                                    WQ_w, wgamma_w, hlie_w, gdown_w, ws);
    kB_chain<<<8, 256, 0, stream>>>(G_t, WQ_b, WK_w, hlie_b, ws);
    kC_scores<<<32, 256, 0, stream>>>(B_t, ws);
    kD_mid<<<8, 256, 0, stream>>>(B_t, WV_w, WV_b, WC_w, WC_b, WG_w, WG_b,
                                  wgamma_w, wgamma_b, Sigma_inv, ws);
    k5a_group<<<393, 256, 0, stream>>>(E, ws);
    k5b_wo<<<1571, 256, 0, stream>>>(WO_w, ws, out);
    k6a_scan<<<32, 256, 0, stream>>>(out, ws);
    k6b_final<<<8, 256, 0, stream>>>(h_t, A_t, E, e_mask, G_t, wmu_w, wmu_b, ws, out);
}

// Round 6
// 513.678 us; speedup vs baseline: 2.7099x; 2.7099x over previous
//
#include <hip/hip_runtime.h>
#include <math.h>

// ---------------- problem constants ----------------
#define NV    50257
#define OUT_M 402056            // 8*50257
#define OUT_A 402568            // + 8*64
#define SCALE 0.125f            // 1/sqrt(64)

// ---------------- ws layout (float offsets) ----------------
#define WS_Q      0             // [8][64][64]
#define WS_HTR    32768         // [1024][8]
#define WS_S      40960         // [64][64]  S = WG Sigma WG^T
#define WS_TV     45056         // [64]
#define WS_C0     45120         // [1]
#define WS_HLIE   47144         // [8][64]
#define WS_W1     47656         // [8][64]
#define WS_GH     48176         // [8]
#define WS_WMAT   48192         // [8][64][64]  W = Q G Q^T
#define WS_SC     80960         // [8][256] scores
#define WS_WB     83008         // [8][64]
#define WS_CONSTB 83520         // [8]
#define WS_GAMMA  83528         // [8]
#define WS_CT     83536         // [8][64]
#define WS_P6     84048         // [8][4][20] top-k partials
// partial-GEMV regions
#define WS_PQT    86016         // [16][8][64]  q_t partials
#define WS_PHL    94208         // [16][8][64]  h_lie partials
#define WS_PGH    102400        // [16][8]      gamma_h partials
#define WS_PGP    102528        // [32][8][64]  g_proj partials
#define WS_PGG    118912        // [32][8]      gamma_tri partials
#define WS_GL     131072        // [8][NV] gamma-folded group logits

// =====================================================================
// kA: 57 blocks.
//   0..7   : Gauss-Jordan (I-A)Q=(I+A) per batch (+ htr write)
//   8      : S = WG Sigma WG^T, tvec, c0
//   9..24  : h-GEMV partials (WQ/hlie/wgamma read ONCE)
//   25..56 : gdown partials (gdown read ONCE)
// =====================================================================
__global__ __launch_bounds__(256) void kA_prep(
    const float* __restrict__ h_t, const float* __restrict__ A_t,
    const float* __restrict__ WG_w, const float* __restrict__ WG_b,
    const float* __restrict__ Sigma_inv,
    const float* __restrict__ WQ_w, const float* __restrict__ wgamma_w,
    const float* __restrict__ hlie_w, const float* __restrict__ gdown_w,
    float* __restrict__ ws)
{
    __shared__ float Ash[64][65];
    __shared__ float Gsh[64][65];
    __shared__ float hsh[1024];
    __shared__ float piv[2][132];
    __shared__ float fr[2][64];
    __shared__ float dsh[64];

    const int tid = threadIdx.x;
    const int blk = blockIdx.x;

    if (blk < 8) {
        // ---------- Gauss-Jordan ----------
        const int b  = blk;
        const int i  = tid & 63;
        const int cb = __builtin_amdgcn_readfirstlane(tid >> 6);

        for (int idx = tid; idx < 4096; idx += 256)
            Ash[idx >> 6][idx & 63] = A_t[b*4096 + idx];
        for (int k = tid; k < 1024; k += 256)
            ws[WS_HTR + k*8 + b] = h_t[b*1024 + k];
        __syncthreads();

        float w[32];
        if (cb < 2) {
            #pragma unroll
            for (int jj = 0; jj < 32; ++jj) {
                int j = cb*32 + jj;
                w[jj] = (i == j ? 1.0f : 0.0f) - Ash[i][j];
            }
        } else {
            #pragma unroll
            for (int jj = 0; jj < 32; ++jj) {
                int j = (cb - 2)*32 + jj;
                w[jj] = (i == j ? 1.0f : 0.0f) + Ash[i][j];
            }
        }
        __syncthreads();

        #pragma unroll
        for (int k = 0; k < 64; ++k) {
            const int kb  = k >> 5;
            const int sel = k & 1;
            if (cb == kb) fr[sel][i] = w[k & 31];
            if (i == k) {
                #pragma unroll
                for (int q4 = 0; q4 < 8; ++q4)
                    *(float4*)&piv[sel][cb*32 + q4*4] =
                        make_float4(w[q4*4], w[q4*4+1], w[q4*4+2], w[q4*4+3]);
            }
            __syncthreads();
            float pk = piv[sel][k];
            float f = (i == k) ? 0.0f : (fr[sel][i] / pk);
            #pragma unroll
            for (int jj = 0; jj < 32; ++jj)
                w[jj] -= f * piv[sel][cb*32 + jj];
        }

        if (cb == (i >> 5)) dsh[i] = w[i & 31];
        __syncthreads();
        if (cb >= 2) {
            float dinv = 1.0f / dsh[i];
            #pragma unroll
            for (int jj = 0; jj < 32; ++jj)
                Ash[i][(cb - 2)*32 + jj] = w[jj] * dinv;   // Ash := Q
        }
        __syncthreads();
        for (int idx = tid; idx < 4096; idx += 256)
            ws[WS_Q + b*4096 + idx] = Ash[idx >> 6][idx & 63];
        return;
    }

    if (blk == 8) {
        // ---------- S = WG Sigma WG^T, tvec, c0 ----------
        const int a   = tid & 63;
        const int cb8 = __builtin_amdgcn_readfirstlane(tid >> 6);
        float* sig = hsh;
        float* bg  = hsh + 64;
        if (tid < 64) { sig[tid] = Sigma_inv[tid]; bg[tid] = WG_b[tid]; }
        __syncthreads();
        for (int idx = tid; idx < 4096; idx += 256) {
            int r = idx >> 6, c = idx & 63;
            float wv = WG_w[idx];
            Gsh[r][c] = wv;            // Wr
            Ash[r][c] = wv * sig[c];   // Wsc
        }
        __syncthreads();
        float t8[16];
        #pragma unroll
        for (int j = 0; j < 16; ++j) t8[j] = 0.0f;
        for (int p = 0; p < 64; ++p) {
            float wv = Ash[a][p];
            #pragma unroll
            for (int jj = 0; jj < 16; ++jj) t8[jj] = fmaf(wv, Gsh[cb8*16 + jj][p], t8[jj]);
        }
        #pragma unroll
        for (int jj = 0; jj < 16; ++jj)
            ws[WS_S + a*64 + cb8*16 + jj] = t8[jj];
        if (cb8 == 0) {
            float s = 0.0f;
            for (int p = 0; p < 64; ++p) s += Ash[a][p] * bg[p];
            ws[WS_TV + a] = 2.0f * s;
        }
        if (tid == 0) {
            float c0 = 0.0f;
            for (int p = 0; p < 64; ++p) c0 += sig[p] * bg[p] * bg[p];
            ws[WS_C0] = c0;
        }
        return;
    }

    if (blk < 25) {
        // ---------- h-GEMV partials, chunk c ----------
        const int c = blk - 9;
        const int i = tid & 63;
        const int w = __builtin_amdgcn_readfirstlane(tid >> 6);
        for (int idx = tid; idx < 4096; idx += 256) {
            int r = idx >> 6, col = idx & 63;
            int krow = c*64 + r;
            Ash[r][col] = WQ_w[krow*64 + col];
            Gsh[r][col] = hlie_w[krow*64 + col];
        }
        for (int t = tid; t < 512; t += 256) {
            int b = t >> 6, kk = t & 63;
            hsh[b*64 + kk] = h_t[b*1024 + c*64 + kk];
        }
        if (tid < 64) dsh[tid] = wgamma_w[c*64 + tid];
        __syncthreads();
        const int b0 = 2*w, b1 = 2*w + 1;
        float q0 = 0, q1 = 0, l0 = 0, l1 = 0;
        #pragma unroll 8
        for (int kk = 0; kk < 64; ++kk) {
            float a = Ash[kk][i], g = Gsh[kk][i];
            float h0 = hsh[b0*64 + kk], h1 = hsh[b1*64 + kk];
            q0 = fmaf(h0, a, q0); q1 = fmaf(h1, a, q1);
            l0 = fmaf(h0, g, l0); l1 = fmaf(h1, g, l1);
        }
        ws[WS_PQT + (c*8 + b0)*64 + i] = q0;
        ws[WS_PQT + (c*8 + b1)*64 + i] = q1;
        ws[WS_PHL + (c*8 + b0)*64 + i] = l0;
        ws[WS_PHL + (c*8 + b1)*64 + i] = l1;
        float g0 = hsh[b0*64 + i] * dsh[i];
        float g1 = hsh[b1*64 + i] * dsh[i];
        #pragma unroll
        for (int off = 32; off > 0; off >>= 1) {
            g0 += __shfl_xor(g0, off);
            g1 += __shfl_xor(g1, off);
        }
        if (i == 0) {
            ws[WS_PGH + c*8 + b0] = g0;
            ws[WS_PGH + c*8 + b1] = g1;
        }
        return;
    }

    // ---------- gdown partials, chunk c ----------
    {
        const int c = blk - 25;
        const int i = tid & 63;
        const int w = __builtin_amdgcn_readfirstlane(tid >> 6);
        for (int idx = tid; idx < 4032; idx += 256) {
            int r = idx >> 6, col = idx & 63;
            Ash[r][col] = gdown_w[(c*63 + r)*64 + col];
        }
        for (int t = tid; t < 504; t += 256) {
            int b = t / 63, sl = t % 63;
            int s = c*63 + sl;
            int i2 = 0, f = 0;
            while (f + (63 - i2) <= s) { f += 63 - i2; ++i2; }
            int j2 = i2 + 1 + (s - f);
            hsh[b*63 + sl] = A_t[b*4096 + i2*64 + j2];
        }
        if (tid < 63) dsh[tid] = wgamma_w[1088 + c*63 + tid];
        __syncthreads();
        const int b0 = 2*w, b1 = 2*w + 1;
        float a0 = 0, a1 = 0;
        #pragma unroll 4
        for (int sl = 0; sl < 63; ++sl) {
            float gd = Ash[sl][i];
            a0 = fmaf(hsh[b0*63 + sl], gd, a0);
            a1 = fmaf(hsh[b1*63 + sl], gd, a1);
        }
        ws[WS_PGP + (c*8 + b0)*64 + i] = a0;
        ws[WS_PGP + (c*8 + b1)*64 + i] = a1;
        float g0 = (i < 63) ? hsh[b0*63 + i] * dsh[i] : 0.0f;
        float g1 = (i < 63) ? hsh[b1*63 + i] * dsh[i] : 0.0f;
        #pragma unroll
        for (int off = 32; off > 0; off >>= 1) {
            g0 += __shfl_xor(g0, off);
            g1 += __shfl_xor(g1, off);
        }
        if (i == 0) {
            ws[WS_PGG + c*8 + b0] = g0;
            ws[WS_PGG + c*8 + b1] = g1;
        }
    }
}

// =====================================================================
// kB: 8 blocks, per batch: reduce h-GEMV partials -> qt, hl, gamma_h;
//     chain qkv -> ghl -> v0 -> w1; W = Q G Q^T -> ws.
// =====================================================================
__global__ __launch_bounds__(256) void kB_chain(
    const float* __restrict__ G_t,
    const float* __restrict__ WQ_b, const float* __restrict__ WK_w,
    const float* __restrict__ hlie_b,
    float* __restrict__ ws)
{
    __shared__ float Qsh[64][65], Gsh[64][65];
    __shared__ float part[4][64], partb[4][64];
    __shared__ float qt[64], hl[64], qkv[64], v0[64];
    __shared__ float red16[16];

    const int b = blockIdx.x, tid = threadIdx.x;
    const int i = tid & 63;
    const int cb = __builtin_amdgcn_readfirstlane(tid >> 6);
    const int col0 = cb * 16;

    for (int idx = tid; idx < 4096; idx += 256) {
        int r = idx >> 6, c = idx & 63;
        Qsh[r][c] = ws[WS_Q + b*4096 + idx];
        Gsh[r][c] = G_t[b*4096 + idx];
    }
    {
        float aq = 0, ah = 0;
        #pragma unroll
        for (int cc = 0; cc < 4; ++cc) {
            int c = cb*4 + cc;
            aq += ws[WS_PQT + (c*8 + b)*64 + i];
            ah += ws[WS_PHL + (c*8 + b)*64 + i];
        }
        part[cb][i] = aq; partb[cb][i] = ah;
    }
    if (tid < 16) red16[tid] = ws[WS_PGH + tid*8 + b];
    __syncthreads();
    if (tid < 64) {
        qt[tid] = part[0][tid]+part[1][tid]+part[2][tid]+part[3][tid] + WQ_b[tid];
        hl[tid] = partb[0][tid]+partb[1][tid]+partb[2][tid]+partb[3][tid] + hlie_b[tid];
    }
    if (tid == 0) {
        float s = 0;
        #pragma unroll
        for (int j = 0; j < 16; ++j) s += red16[j];
        ws[WS_GH + b] = s;
    }
    __syncthreads();
    {
        float acc = 0;
        #pragma unroll
        for (int jj = 0; jj < 16; ++jj)
            acc = fmaf(WK_w[i*64 + col0 + jj], qt[col0 + jj], acc);
        part[cb][i] = acc;
    }
    __syncthreads();
    if (tid < 64) qkv[tid] = part[0][tid]+part[1][tid]+part[2][tid]+part[3][tid];
    __syncthreads();
    {
        float acc = 0;
        #pragma unroll
        for (int jj = 0; jj < 16; ++jj)
            acc = fmaf(Gsh[i][col0 + jj], hl[col0 + jj], acc);
        part[cb][i] = acc;
    }
    __syncthreads();
    if (tid < 64)
        v0[tid] = SCALE*qkv[tid] + part[0][tid]+part[1][tid]+part[2][tid]+part[3][tid];
    __syncthreads();
    {
        float acc = 0;
        #pragma unroll
        for (int jj = 0; jj < 16; ++jj)
            acc = fmaf(Qsh[i][col0 + jj], v0[col0 + jj], acc);
        part[cb][i] = acc;
    }
    __syncthreads();
    if (tid < 64) {
        ws[WS_W1 + b*64 + tid]   = part[0][tid]+part[1][tid]+part[2][tid]+part[3][tid];
        ws[WS_HLIE + b*64 + tid] = hl[tid];
    }
    float tt[16];
    #pragma unroll
    for (int j = 0; j < 16; ++j) tt[j] = 0;
    for (int r = 0; r < 64; ++r) {
        float qv = Qsh[i][r];
        #pragma unroll
        for (int j = 0; j < 16; ++j) tt[j] = fmaf(qv, Gsh[r][col0 + j], tt[j]);
    }
    __syncthreads();
    #pragma unroll
    for (int j = 0; j < 16; ++j) Gsh[i][col0 + j] = tt[j];   // Gsh := T
    __syncthreads();
    float w2r[16];
    #pragma unroll
    for (int j = 0; j < 16; ++j) w2r[j] = 0;
    for (int q = 0; q < 64; ++q) {
        float tv = Gsh[i][q];
        #pragma unroll
        for (int j = 0; j < 16; ++j) w2r[j] = fmaf(tv, Qsh[col0 + j][q], w2r[j]);
    }
    #pragma unroll
    for (int j = 0; j < 16; ++j)
        ws[WS_WMAT + b*4096 + (col0 + j)*64 + i] = w2r[j];
}

// =====================================================================
// kC: 32 blocks = (b, quarter). scores via b W b^T from LDS.
// =====================================================================
__global__ __launch_bounds__(256) void kC_scores(
    const float* __restrict__ B_t, float* __restrict__ ws)
{
    __shared__ float Bsh[64][65];
    __shared__ float Wsh[64][64];
    __shared__ float w1sh[64];
    __shared__ float part[4][64];
    const int b = blockIdx.x >> 2, q4 = blockIdx.x & 3;
    const int tid = threadIdx.x, lane = tid & 63;
    const int gu = __builtin_amdgcn_readfirstlane(tid >> 6);
    const int col0 = gu * 16;
    for (int idx = tid; idx < 4096; idx += 256) {
        int r = idx >> 6, c = idx & 63;
        Bsh[r][c] = B_t[b*16384 + (q4*64 + r)*64 + c];
        Wsh[r][c] = ws[WS_WMAT + b*4096 + idx];
    }
    if (tid < 64) w1sh[tid] = ws[WS_W1 + b*64 + tid];
    __syncthreads();
    float t[16];
    #pragma unroll
    for (int j = 0; j < 16; ++j) t[j] = 0;
    for (int p = 0; p < 64; ++p) {
        float bv = Bsh[lane][p];
        #pragma unroll
        for (int j = 0; j < 16; ++j) t[j] = fmaf(bv, Wsh[p][col0 + j], t[j]);
    }
    float ps = 0;
    #pragma unroll
    for (int j = 0; j < 16; ++j) ps += (w1sh[col0+j] - 0.5f*t[j]) * Bsh[lane][col0+j];
    part[gu][lane] = ps;
    __syncthreads();
    if (tid < 64)
        ws[WS_SC + b*256 + q4*64 + tid] =
            part[0][tid]+part[1][tid]+part[2][tid]+part[3][tid];
}

// =====================================================================
// kD: per batch: softmax(alpha), c chain, g_proj (partial reduce),
//     gamma, w_b.
// =====================================================================
__global__ __launch_bounds__(256) void kD_mid(
    const float* __restrict__ B_t,
    const float* __restrict__ WV_w, const float* __restrict__ WV_b,
    const float* __restrict__ WC_w, const float* __restrict__ WC_b,
    const float* __restrict__ WG_w, const float* __restrict__ WG_b,
    const float* __restrict__ wgamma_w, const float* __restrict__ wgamma_b,
    const float* __restrict__ Sigma_inv,
    float* __restrict__ ws)
{
    __shared__ float alpha[256], rr[256];
    __shared__ float part[4][64];
    __shared__ float cBr[64], cB[64], ct[64], cw[64], crot[64], gp[64], uv[64];
    __shared__ float red32[32];
    const int b = blockIdx.x, tid = threadIdx.x, lane = tid & 63;
    const int gu = __builtin_amdgcn_readfirstlane(tid >> 6);
    const int col0 = gu * 16;
    const float* Qb = ws + WS_Q + b*4096;

    float sv = ws[WS_SC + b*256 + tid];
    rr[tid] = sv;
    if (tid < 32) red32[tid] = ws[WS_PGG + tid*8 + b];
    __syncthreads();
    for (int off = 128; off > 0; off >>= 1) { if (tid < off) rr[tid] = fmaxf(rr[tid], rr[tid+off]); __syncthreads(); }
    float smax = rr[0]; __syncthreads();
    float e = expf(sv - smax);
    rr[tid] = e; __syncthreads();
    for (int off = 128; off > 0; off >>= 1) { if (tid < off) rr[tid] += rr[tid+off]; __syncthreads(); }
    float den = rr[0]; __syncthreads();
    alpha[tid] = e / den;
    __syncthreads();
    {
        float acc = 0;
        for (int nn = 0; nn < 64; ++nn) {
            int n = gu*64 + nn;
            acc = fmaf(alpha[n], B_t[b*16384 + n*64 + lane], acc);
        }
        part[gu][lane] = acc;
    }
    __syncthreads();
    if (tid < 64) cBr[tid] = part[0][tid]+part[1][tid]+part[2][tid]+part[3][tid];
    __syncthreads();
    {
        float acc = 0;
        #pragma unroll
        for (int pp = 0; pp < 16; ++pp) { int p = col0+pp; acc = fmaf(cBr[p], Qb[p*64+lane], acc); }
        part[gu][lane] = acc;
    }
    __syncthreads();
    if (tid < 64) cB[tid] = part[0][tid]+part[1][tid]+part[2][tid]+part[3][tid];
    __syncthreads();
    {
        float acc = 0;
        #pragma unroll
        for (int pp = 0; pp < 16; ++pp) { int p = col0+pp; acc = fmaf(cB[p], WV_w[p*64+lane], acc); }
        part[gu][lane] = acc;
    }
    __syncthreads();
    if (tid < 64) {
        float v = part[0][tid]+part[1][tid]+part[2][tid]+part[3][tid] + WV_b[tid];
        ct[tid] = v; ws[WS_CT + b*64 + tid] = v;
    }
    __syncthreads();
    {
        float acc = 0;
        #pragma unroll
        for (int pp = 0; pp < 16; ++pp) { int p = col0+pp; acc = fmaf(ct[p], WC_w[p*64+lane], acc); }
        part[gu][lane] = acc;
    }
    __syncthreads();
    if (tid < 64) cw[tid] = part[0][tid]+part[1][tid]+part[2][tid]+part[3][tid] + WC_b[tid];
    __syncthreads();
    {
        float acc = 0;
        #pragma unroll
        for (int pp = 0; pp < 16; ++pp) { int p = col0+pp; acc = fmaf(cw[p], Qb[p*64+lane], acc); }
        part[gu][lane] = acc;
    }
    __syncthreads();
    if (tid < 64) crot[tid] = part[0][tid]+part[1][tid]+part[2][tid]+part[3][tid];
    __syncthreads();
    {
        float acc = 0;
        #pragma unroll
        for (int cc = 0; cc < 8; ++cc) {
            int c = gu*8 + cc;
            acc += ws[WS_PGP + (c*8 + b)*64 + lane];
        }
        part[gu][lane] = acc;
    }
    if (tid < 64) rr[64 + tid] = ct[tid] * wgamma_w[1024 + tid];
    __syncthreads();
    if (tid < 64) {
        float g = part[0][tid]+part[1][tid]+part[2][tid]+part[3][tid];
        gp[tid] = g; uv[tid] = 2.0f * Sigma_inv[tid] * g;
    }
    if (tid == 0) {
        float gc = 0;
        for (int j = 0; j < 64; ++j) gc += rr[64 + j];
        float ga = 0;
        for (int j = 0; j < 32; ++j) ga += red32[j];
        float z = ws[WS_GH + b] + gc + ga + wgamma_b[0];
        ws[WS_GAMMA + b] = 1.0f / (1.0f + expf(-z));
    }
    __syncthreads();
    {
        float acc = 0;
        #pragma unroll
        for (int pp = 0; pp < 16; ++pp) { int p = col0+pp; acc = fmaf(WG_w[lane*64+p], uv[p], acc); }
        part[gu][lane] = acc;
    }
    if (tid < 64) rr[tid] = WG_b[tid]*uv[tid] - gp[tid]*gp[tid]*Sigma_inv[tid];
    __syncthreads();
    if (tid < 64)
        ws[WS_WB + b*64 + tid] = SCALE*crot[tid]
            + part[0][tid]+part[1][tid]+part[2][tid]+part[3][tid];
    if (tid == 0) { float s = 0; for (int j = 0; j < 64; ++j) s += rr[j]; ws[WS_CONSTB + b] = s; }
}

// =====================================================================
// k5a: group-logit side. 393 blocks x 256 thr, 128 v/block (2 thr/v).
//      E read once; writes gl[b][v] = gamma_b*(gd + const_b - sv) to ws.
// =====================================================================
__global__ __launch_bounds__(256) void k5a_group(
    const float* __restrict__ E, float* __restrict__ ws)
{
    __shared__ float smem[14544];   // 58.2 KB
    const int tid  = threadIdx.x;
    const int half = tid >> 7;
    const int vt   = tid & 127;
    const int vb = blockIdx.x * 128;
    const int v = vb + vt;
    const bool vok = v < NV;

    float* Esh  = smem;            // [128][66]
    float* Ssh  = smem + 8448;     // [64][64]
    float* tvsh = smem + 12544;    // [64]
    float* wbsh = smem + 12608;    // [8][64]
    float* gmsh = smem + 13120;    // [8]
    float* cbsh = smem + 13128;    // [8]
    float* svsh = smem + 13136;    // [2][128]
    float* gdsh = smem + 13392;    // [128][9]

    for (int idx = tid; idx < 2048; idx += 256) {
        int r = idx >> 4, c4 = (idx & 15) * 4;
        int vr = vb + r; if (vr >= NV) vr = NV - 1;
        float4 e4 = *(const float4*)(E + (size_t)vr * 64 + c4);
        float* dst = Esh + r*66 + c4;
        dst[0] = e4.x; dst[1] = e4.y; dst[2] = e4.z; dst[3] = e4.w;
    }
    for (int idx = tid; idx < 4096; idx += 256) Ssh[idx] = ws[WS_S + idx];
    for (int idx = tid; idx < 512; idx += 256) wbsh[idx] = ws[WS_WB + idx];
    if (tid < 64) tvsh[tid] = ws[WS_TV + tid];
    if (tid < 8) { gmsh[tid] = ws[WS_GAMMA + tid]; cbsh[tid] = ws[WS_CONSTB + tid]; }
    __syncthreads();
    {
        const float* er = Esh + vt*66;
        float sv = (half == 0) ? ws[WS_C0] : 0.0f;
        #pragma unroll
        for (int jj = 0; jj < 2; ++jj) {
            const int jb = half*2 + jj;
            float t[16];
            #pragma unroll
            for (int j = 0; j < 16; ++j) t[j] = 0.0f;
            for (int p = 0; p < 64; ++p) {
                float ep = er[p];
                #pragma unroll
                for (int j = 0; j < 16; ++j)
                    t[j] = fmaf(ep, Ssh[p*64 + jb*16 + j], t[j]);
            }
            #pragma unroll
            for (int j = 0; j < 16; ++j)
                sv += (t[j] + tvsh[jb*16 + j]) * er[jb*16 + j];
        }
        svsh[half*128 + vt] = sv;
        const float* w0 = wbsh + (half*4    )*64;
        const float* w1 = wbsh + (half*4 + 1)*64;
        const float* w2 = wbsh + (half*4 + 2)*64;
        const float* w3 = wbsh + (half*4 + 3)*64;
        float g0 = 0, g1 = 0, g2 = 0, g3 = 0;
        #pragma unroll 8
        for (int p = 0; p < 64; ++p) {
            float ep = er[p];
            g0 = fmaf(ep, w0[p], g0); g1 = fmaf(ep, w1[p], g1);
            g2 = fmaf(ep, w2[p], g2); g3 = fmaf(ep, w3[p], g3);
        }
        float* gr = gdsh + vt*9 + half*4;
        gr[0] = g0; gr[1] = g1; gr[2] = g2; gr[3] = g3;
    }
    __syncthreads();
    if (half == 0 && vok) {
        float svt = svsh[vt] + svsh[128 + vt];
        const float* gr = gdsh + vt*9;
        #pragma unroll
        for (int bb = 0; bb < 8; ++bb)
            ws[WS_GL + bb*NV + v] = gmsh[bb] * (gr[bb] + cbsh[bb] - svt);
    }
}

// =====================================================================
// k5b: pure WO stream. 1571 blocks x 256 thr, 32 v/block, 8-way k-split.
//      NO min-waves launch bound (R5's ",4" forced a 64-VGPR cap ->
//      acc/wr spilled to scratch -> 3 GB of scratch traffic, 990 us).
//      KU5=8 keeps register demand low; natural VGPR alloc, zero spill.
//      out[b][v] = sum_k h[k][b]*WO[k][v] + gl[b][v].
// =====================================================================
#define KU5 8
__global__ __launch_bounds__(256) void k5b_wo(
    const float* __restrict__ WO_w,
    const float* __restrict__ ws, float* __restrict__ out)
{
    __shared__ float hsh[8192];     // [1024][8]; tail reused as reduce buf
    const int tid = threadIdx.x;
    const int vt  = tid & 31;
    const int kg  = tid >> 5;       // 0..7
    const int vb  = blockIdx.x * 32;
    const int v   = vb + vt;
    const bool vok = v < NV;
    const int vv = vok ? v : NV - 1;

    for (int idx = tid; idx < 2048; idx += 256)
        *(float4*)(hsh + idx*4) = *(const float4*)(ws + WS_HTR + idx*4);
    __syncthreads();

    float acc[8];
    #pragma unroll
    for (int bb = 0; bb < 8; ++bb) acc[bb] = 0.0f;
    {
        const float* wo = WO_w + (size_t)(kg * 128) * NV + vv;
        const float* hb = hsh + kg*128*8;
        for (int k0 = 0; k0 < 128; k0 += KU5) {
            float wr[KU5];
            #pragma unroll
            for (int u = 0; u < KU5; ++u) wr[u] = wo[(size_t)(k0 + u) * NV];
            #pragma unroll
            for (int u = 0; u < KU5; ++u) {
                const float* hp = hb + (k0 + u)*8;
                #pragma unroll
                for (int bb = 0; bb < 8; ++bb) acc[bb] = fmaf(hp[bb], wr[u], acc[bb]);
            }
        }
    }
    // prefetch gl for the combining threads (hidden under reduction)
    float gl[8];
    if (kg == 0) {
        #pragma unroll
        for (int bb = 0; bb < 8; ++bb) gl[bb] = ws[WS_GL + bb*NV + vv];
    }
    __syncthreads();               // all hsh reads done; reuse as reduce buf
    float* red = hsh;              // [4][32][8]
    if (kg >= 4) {
        float* r = red + ((kg - 4)*32 + vt)*8;
        #pragma unroll
        for (int bb = 0; bb < 8; ++bb) r[bb] = acc[bb];
    }
    __syncthreads();
    if (kg < 4) {
        const float* r = red + (kg*32 + vt)*8;
        #pragma unroll
        for (int bb = 0; bb < 8; ++bb) acc[bb] += r[bb];
    }
    __syncthreads();
    if (kg >= 2 && kg < 4) {
        float* r = red + ((kg - 2)*32 + vt)*8;
        #pragma unroll
        for (int bb = 0; bb < 8; ++bb) r[bb] = acc[bb];
    }
    __syncthreads();
    if (kg < 2) {
        const float* r = red + (kg*32 + vt)*8;
        #pragma unroll
        for (int bb = 0; bb < 8; ++bb) acc[bb] += r[bb];
    }
    __syncthreads();
    if (kg == 1) {
        float* r = red + vt*8;
        #pragma unroll
        for (int bb = 0; bb < 8; ++bb) r[bb] = acc[bb];
    }
    __syncthreads();
    if (kg == 0 && vok) {
        const float* r = red + vt*8;
        #pragma unroll
        for (int bb = 0; bb < 8; ++bb)
            out[bb*NV + v] = acc[bb] + r[bb] + gl[bb];
    }
}

// =====================================================================
// K6a: 32 blocks = (b, quarter). Single pass: per-thread top-8 + online
// (m,s1,s2); wave shfl extraction; 4-list merge; shfl sum reduce.
// =====================================================================
#define NQ 12565
__global__ __launch_bounds__(256) void k6a_scan(
    const float* __restrict__ outl, float* __restrict__ ws)
{
    __shared__ float mvw[4][8];
    __shared__ int   miw[4][8];
    __shared__ float t8v[8];
    __shared__ int   t8i[8];
    __shared__ float redv[4], sred[4];
    const int b = blockIdx.x >> 2, qq = blockIdx.x & 3;
    const int tid = threadIdx.x, lane = tid & 63, wvi = tid >> 6;
    const int v0 = qq * NQ;
    const int v1 = (v0 + NQ < NV) ? (v0 + NQ) : NV;
    const float* lg = outl + b*NV;

    float lv[8]; int li[8];
    #pragma unroll
    for (int u = 0; u < 8; ++u) { lv[u] = -INFINITY; li[u] = 0x7fffffff; }
    float mt = -INFINITY, s1 = 0.0f, s2 = 0.0f;
    for (int v = v0 + tid; v < v1; v += 256) {
        float x = lg[v];
        if (x > mt) {
            float r = expf(mt - x);
            s1 *= r; s2 *= r; mt = x;
        }
        float ee = expf(x - mt);
        s1 += ee; s2 += x * ee;
        if (x > lv[7]) {
            float cv = x; int ci = v;
            #pragma unroll
            for (int u = 0; u < 8; ++u) {
                if (cv > lv[u]) {
                    float tv = lv[u]; lv[u] = cv; cv = tv;
                    int   ti = li[u]; li[u] = ci; ci = ti;
                }
            }
        }
    }
    float wv8[8]; int wi8[8];
    #pragma unroll
    for (int it = 0; it < 8; ++it) {
        float bv = lv[0]; int bi = li[0];
        #pragma unroll
        for (int off = 32; off > 0; off >>= 1) {
            float ov = __shfl_xor(bv, off);
            int   oi = __shfl_xor(bi, off);
            if (ov > bv || (ov == bv && oi < bi)) { bv = ov; bi = oi; }
        }
        wv8[it] = bv; wi8[it] = bi;
        if (lv[0] == bv && li[0] == bi) {
            lv[0]=lv[1]; lv[1]=lv[2]; lv[2]=lv[3]; lv[3]=lv[4];
            lv[4]=lv[5]; lv[5]=lv[6]; lv[6]=lv[7]; lv[7]=-INFINITY;
            li[0]=li[1]; li[1]=li[2]; li[2]=li[3]; li[3]=li[4];
            li[4]=li[5]; li[5]=li[6]; li[6]=li[7]; li[7]=0x7fffffff;
        }
    }
    if (lane == 0) {
        #pragma unroll
        for (int u = 0; u < 8; ++u) { mvw[wvi][u] = wv8[u]; miw[wvi][u] = wi8[u]; }
    }
    __syncthreads();
    if (tid == 0) {
        int pA = 0, pB = 0, pC = 0, pD = 0;
        for (int it = 0; it < 8; ++it) {
            float vA = mvw[0][pA], vB = mvw[1][pB], vC = mvw[2][pC], vD = mvw[3][pD];
            int   iA = miw[0][pA], iB = miw[1][pB], iC = miw[2][pC], iD = miw[3][pD];
            float best = vA; int bi = iA; int w = 0;
            if (vB > best || (vB == best && iB < bi)) { best = vB; bi = iB; w = 1; }
            if (vC > best || (vC == best && iC < bi)) { best = vC; bi = iC; w = 2; }
            if (vD > best || (vD == best && iD < bi)) { best = vD; bi = iD; w = 3; }
            t8v[it] = best; t8i[it] = bi;
            if (w == 0) ++pA; else if (w == 1) ++pB; else if (w == 2) ++pC; else ++pD;
        }
    }
    __syncthreads();
    float Mp = t8v[0];
    {
        float r = expf(mt - Mp);
        s1 *= r; s2 *= r;
    }
    #pragma unroll
    for (int off = 32; off > 0; off >>= 1) {
        s1 += __shfl_xor(s1, off);
        s2 += __shfl_xor(s2, off);
    }
    if (lane == 0) { redv[wvi] = s1; sred[wvi] = s2; }
    __syncthreads();
    if (tid == 0) {
        int base = WS_P6 + (b*4 + qq)*20;
        #pragma unroll
        for (int u = 0; u < 8; ++u) { ws[base + u] = t8v[u]; ((int*)ws)[base + 8 + u] = t8i[u]; }
        ws[base + 16] = Mp;
        ws[base + 17] = redv[0]+redv[1]+redv[2]+redv[3];
        ws[base + 18] = sred[0]+sred[1]+sred[2]+sred[3];
    }
}

// =====================================================================
// K6b: per batch: merge partials, H, E_exp, rho, mu, m_next, A_next
// =====================================================================
__global__ __launch_bounds__(256) void k6b_final(
    const float* __restrict__ h_t, const float* __restrict__ A_t,
    const float* __restrict__ E, const float* __restrict__ e_mask,
    const float* __restrict__ G_t,
    const float* __restrict__ wmu_w, const float* __restrict__ wmu_b,
    const float* __restrict__ ws, float* __restrict__ out)
{
    __shared__ float mv[32];
    __shared__ int   mi[32];
    __shared__ float t8v[8];
    __shared__ int   t8i[8];
    __shared__ float toppsh[8];
    __shared__ float redv[256];
    __shared__ float uvec[64], eexp[64], msh[64], emsh[64];
    __shared__ float scal[4];
    const int b = blockIdx.x, tid = threadIdx.x;

    if (tid < 32) {
        int base = WS_P6 + (b*4 + (tid >> 3))*20;
        mv[tid] = ws[base + (tid & 7)];
        mi[tid] = ((const int*)ws)[base + 8 + (tid & 7)];
    }
    __syncthreads();
    if (tid == 0) {
        unsigned used = 0;
        for (int it = 0; it < 8; ++it) {
            float best = -INFINITY; int bi = 0x7fffffff, bs = 0;
            for (int c = 0; c < 32; ++c) {
                if (used & (1u << c)) continue;
                float x = mv[c];
                if (x > best || (x == best && mi[c] < bi)) { best = x; bi = mi[c]; bs = c; }
            }
            used |= 1u << bs; t8v[it] = best; t8i[it] = bi;
        }
        float M = t8v[0];
        float s1 = 0, s2 = 0;
        for (int q = 0; q < 4; ++q) {
            int base = WS_P6 + (b*4 + q)*20;
            float sc_ = expf(ws[base + 16] - M);
            s1 += ws[base + 17] * sc_; s2 += ws[base + 18] * sc_;
        }
        scal[0] = M + logf(s1) - s2 / s1;       // H
        float ts = 0, tv_[8];
        #pragma unroll
        for (int u = 0; u < 8; ++u) { tv_[u] = expf(t8v[u] - M); ts += tv_[u]; }
        #pragma unroll
        for (int u = 0; u < 8; ++u) toppsh[u] = tv_[u] / ts;
    }
    __syncthreads();
    if (tid < 64) {
        float u_ = 0;
        #pragma unroll
        for (int j = 0; j < 8; ++j) u_ += toppsh[j] * E[t8i[j]*64 + tid];
        uvec[tid] = u_;
    }
    __syncthreads();
    if (tid < 64) {
        const float* Qb = ws + WS_Q + b*4096;
        float a = 0;
        for (int p = 0; p < 64; ++p) a += uvec[p] * Qb[p*64 + tid];
        eexp[tid] = a;
    }
    __syncthreads();
    {   // rho
        const float* Gb = G_t + b*4096;
        const float* HL = ws + WS_HLIE + b*64;
        float a = 0;
        #pragma unroll 4
        for (int t2 = 0; t2 < 16; ++t2) {
            int idx = tid*16 + t2;
            int p = idx >> 6, q = idx & 63;
            a += (eexp[p] - HL[p]) * Gb[idx] * (eexp[q] - HL[q]);
        }
        redv[tid] = a;
    }
    __syncthreads();
    for (int off = 128; off > 0; off >>= 1) {
        if (tid < off) redv[tid] += redv[tid + off];
        __syncthreads();
    }
    if (tid == 0) scal[1] = redv[0];
    __syncthreads();
    // mu
    float pm = 0;
    for (int k = tid; k < 1024; k += 256) pm += h_t[b*1024 + k] * wmu_w[k];
    if (tid < 64) pm += ws[WS_CT + b*64 + tid] * wmu_w[1024 + tid];
    redv[tid] = pm;
    __syncthreads();
    for (int off = 128; off > 0; off >>= 1) {
        if (tid < off) redv[tid] += redv[tid + off];
        __syncthreads();
    }
    if (tid == 0) {
        float z = redv[0] + scal[0]*wmu_w[1088] + scal[1]*wmu_w[1089] + wmu_b[0];
        scal[2] = 1.0f / (1.0f + expf(-z));
    }
    __syncthreads();
    if (tid < 64) {
        float mu = scal[2];
        float em = e_mask[b*64 + tid];
        float m = mu*em + (1.0f - mu)*eexp[tid];
        out[OUT_M + b*64 + tid] = m;
        msh[tid] = m; emsh[tid] = em;
    }
    __syncthreads();
    for (int idx = tid; idx < 4096; idx += 256) {
        int i = idx >> 6, j = idx & 63;
        out[OUT_A + b*4096 + idx] = A_t[b*4096 + idx]
            + 0.1f*(msh[i]*emsh[j] - msh[j]*emsh[i]);
    }
}

// =====================================================================
extern "C" void kernel_launch(void* const* d_in, const int* in_sizes, int n_in,
                              void* d_out, int out_size, void* d_ws, size_t ws_size,
                              hipStream_t stream)
{
    const float* h_t      = (const float*)d_in[0];
    const float* A_t      = (const float*)d_in[1];
    const float* B_t      = (const float*)d_in[2];
    const float* E        = (const float*)d_in[3];
    const float* e_mask   = (const float*)d_in[4];
    const float* G_t      = (const float*)d_in[5];
    const float* WQ_w     = (const float*)d_in[7];
    const float* WQ_b     = (const float*)d_in[8];
    const float* WK_w     = (const float*)d_in[9];
    const float* WV_w     = (const float*)d_in[11];
    const float* WV_b     = (const float*)d_in[12];
    const float* WC_w     = (const float*)d_in[13];
    const float* WC_b     = (const float*)d_in[14];
    const float* WO_w     = (const float*)d_in[15];
    const float* WG_w     = (const float*)d_in[16];
    const float* WG_b     = (const float*)d_in[17];
    const float* wgamma_w = (const float*)d_in[18];
    const float* wgamma_b = (const float*)d_in[19];
    const float* wmu_w    = (const float*)d_in[20];
    const float* wmu_b    = (const float*)d_in[21];
    const float* gdown_w  = (const float*)d_in[22];
    const float* Sigma_inv= (const float*)d_in[23];
    const float* hlie_w   = (const float*)d_in[24];
    const float* hlie_b   = (const float*)d_in[25];
    float* out = (float*)d_out;
    float* ws  = (float*)d_ws;

    kA_prep<<<57, 256, 0, stream>>>(h_t, A_t, WG_w, WG_b, Sigma_inv,
                                    WQ_w, wgamma_w, hlie_w, gdown_w, ws);
    kB_chain<<<8, 256, 0, stream>>>(G_t, WQ_b, WK_w, hlie_b, ws);
    kC_scores<<<32, 256, 0, stream>>>(B_t, ws);
    kD_mid<<<8, 256, 0, stream>>>(B_t, WV_w, WV_b, WC_w, WC_b, WG_w, WG_b,
                                  wgamma_w, wgamma_b, Sigma_inv, ws);
    k5a_group<<<393, 256, 0, stream>>>(E, ws);
    k5b_wo<<<1571, 256, 0, stream>>>(WO_w, ws, out);
    k6a_scan<<<32, 256, 0, stream>>>(out, ws);
    k6b_final<<<8, 256, 0, stream>>>(h_t, A_t, E, e_mask, G_t, wmu_w, wmu_b, ws, out);
}